// Round 11
// baseline (98.826 us; speedup 1.0000x reference)
//
#include <hip/hip_runtime.h>
#include <math.h>

#define NHID 1024
#define NIN 14
#define NKEYS 100000
#define NRD 10
#define R3 100           // rows per PV block; 1000 * 100 = 100000 exactly
#define NB3 1000
#define NBPRE 1280       // 5120 preact rows / 4 per block
#define NSLOT 8
#define GRP 10           // rows per stream group (double-buffered banks)

typedef float f32x4 __attribute__((ext_vector_type(4)));
typedef float f32x2 __attribute__((ext_vector_type(2)));

// ws float-index layout
#define WS_MACC    0         // NSLOT*1024 = 8192 floats
#define WS_L       8192      // NSLOT floats
#define WS_PREACT  8208      // 5120 floats (16B aligned)
#define WS_HH      13328     // 1024
#define ZERO_BYTES ((NSLOT * NHID + NSLOT) * 4)

__device__ inline float wave_reduce_sum(float v) {
#pragma unroll
    for (int off = 32; off > 0; off >>= 1) v += __shfl_down(v, off, 64);
    return v;
}

__device__ inline float sigm(float x) { return 1.0f / (1.0f + expf(-x)); }

__device__ inline float bcast_lane(float v, int lane) {
    return __uint_as_float(__builtin_amdgcn_readlane(__float_as_uint(v), lane));
}

// native f32 atomic add (global_atomic_add_f32), not a CAS loop
__device__ inline void atomAddF(float* p, float v) { unsafeAtomicAdd(p, v); }

// load q (clamped dynamic_slice like JAX) and its norm
__device__ inline float load_q(const float* __restrict__ x, int pick, float* q) {
    int start = pick * NRD;
    if (start > NIN - NRD) start = NIN - NRD;
    if (start < 0) start = 0;
    float qn = 0.f;
#pragma unroll
    for (int k = 0; k < NRD; ++k) { q[k] = x[start + k]; qn = fmaf(q[k], q[k], qn); }
    return sqrtf(qn);
}

// cosine score, f32x2 key loads (rows are 40B -> always 8B aligned)
__device__ inline float score2(const float* __restrict__ keys, int i,
                               const float* q, float qn) {
    const f32x2* kp = (const f32x2*)(keys + (size_t)i * NRD);
    float dot = 0.f, kn = 0.f;
#pragma unroll
    for (int k = 0; k < 5; ++k) {
        f32x2 kv = kp[k];
        dot = fmaf(kv.x, q[2 * k], fmaf(kv.y, q[2 * k + 1], dot));
        kn  = fmaf(kv.x, kv.x, fmaf(kv.y, kv.y, kn));
    }
    return dot / fmaxf(sqrtf(kn) * qn, 1e-8f);
}

// Fused: blocks [0, NB3) do the PV partial reduction (unnormalized; cos-sim
// scores are in [-1,1] so exp(s) is stable, no max pass); blocks
// [NB3, NB3+NBPRE) compute preact rows.
// R11 A/B: vals stream loads are PLAIN (no nontemporal) — single-variable test
// of whether the nt hint caps read BW at L2. Everything else identical to R10.
// NOTE (R7/R9 lesson): NO threadfence/ACQ_REL election anywhere — device-scope
// fences cost ~20 µs at any block count; kernel boundaries are cheaper.
__global__ void __launch_bounds__(256) kA(const float* __restrict__ keys,
                                          const float* __restrict__ x,
                                          const int* __restrict__ pick_arm,
                                          const float* __restrict__ vals,
                                          float* __restrict__ macc,
                                          float* __restrict__ Lacc,
                                          const float* __restrict__ h,
                                          const float* __restrict__ Wi,
                                          const float* __restrict__ bi,
                                          const float* __restrict__ Wh,
                                          const float* __restrict__ bh,
                                          float* __restrict__ preact) {
    int tid = threadIdx.x;
    if (blockIdx.x < NB3) {
        int r0 = blockIdx.x * R3;
        int slot = blockIdx.x & (NSLOT - 1);
        int lane = tid & 63;
        const f32x4* vp = (const f32x4*)vals + ((size_t)r0 << 8) + tid;
        f32x4 bankA[GRP], bankB[GRP];
        // prologue: issue group 0 into bank A before any score work
#pragma unroll
        for (int j = 0; j < GRP; ++j)
            bankA[j] = vp[(size_t)j << 8];
        __builtin_amdgcn_sched_barrier(0);
        // redundant per-wave score computation, all 64 lanes (keys L2-hot)
        float q[NRD];
        float qn = load_q(x, pick_arm[0], q);
        float wva = expf(score2(keys, r0 + lane, q, qn));        // rows 0..63
        float wvb = 0.f;
        if (lane < R3 - 64)                                      // rows 64..99
            wvb = expf(score2(keys, r0 + 64 + lane, q, qn));
        if (tid < 64) {                  // wave 0 contributes the L partial
            float ls = wave_reduce_sum(wva + wvb);
            if (tid == 0) atomAddF(&Lacc[slot], ls);
        }
        float ax = 0.f, ay = 0.f, az = 0.f, aw = 0.f;
#pragma unroll
        for (int g = 0; g < R3 / GRP; ++g) {
            // issue group g+1 into the other bank (static bank choice)
            if (g + 1 < R3 / GRP) {
                if (g & 1) {
#pragma unroll
                    for (int j = 0; j < GRP; ++j)
                        bankA[j] = vp[(size_t)((g + 1) * GRP + j) << 8];
                } else {
#pragma unroll
                    for (int j = 0; j < GRP; ++j)
                        bankB[j] = vp[(size_t)((g + 1) * GRP + j) << 8];
                }
            }
            __builtin_amdgcn_sched_barrier(0);
            // consume group g from this bank
#pragma unroll
            for (int j = 0; j < GRP; ++j) {
                int r = g * GRP + j;
                float w = (r < 64) ? bcast_lane(wva, r) : bcast_lane(wvb, r - 64);
                f32x4 v = (g & 1) ? bankB[j] : bankA[j];
                ax = fmaf(w, v.x, ax);
                ay = fmaf(w, v.y, ay);
                az = fmaf(w, v.z, az);
                aw = fmaf(w, v.w, aw);
            }
            __builtin_amdgcn_sched_barrier(0);
        }
        float* ms = macc + (size_t)slot * NHID;
        atomAddF(&ms[4 * tid + 0], ax);
        atomAddF(&ms[4 * tid + 1], ay);
        atomAddF(&ms[4 * tid + 2], az);
        atomAddF(&ms[4 * tid + 3], aw);
    } else {
        int wave = tid >> 6, lane = tid & 63;
        int row = (blockIdx.x - NB3) * 4 + wave;
        const f32x4* w4 = (const f32x4*)(Wh + (size_t)row * NHID);
        const f32x4* h4 = (const f32x4*)h;
        float p = 0.f;
#pragma unroll
        for (int j = 0; j < 4; ++j) {
            f32x4 wv = __builtin_nontemporal_load(&w4[j * 64 + lane]);
            f32x4 hv = h4[j * 64 + lane];
            p += wv.x * hv.x + wv.y * hv.y + wv.z * hv.z + wv.w * hv.w;
        }
        if (lane < NIN) p += x[lane] * Wi[(size_t)row * NIN + lane];
        p = wave_reduce_sum(p);
        if (lane == 0) preact[row] = p + bi[row] + bh[row];
    }
}

// Fused cell update + hidden GEMV. Every block redundantly computes the full
// 1024-wide cell update (L2-hot inputs), stashes h_t in LDS, then computes its
// 4 rows of hh = relu(W_ih . h_t + b_ih). Block 0 also writes h_t/c_t to out.
__global__ void __launch_bounds__(256) k45(const float* __restrict__ preact,
                                           const float* __restrict__ macc,
                                           const float* __restrict__ Lacc,
                                           const float* __restrict__ c_in,
                                           const float* __restrict__ Wih,
                                           const float* __restrict__ bih,
                                           float* __restrict__ out,
                                           float* __restrict__ hh) {
    __shared__ float hlds[NHID];
    int tid = threadIdx.x;
    float Ls = 0.f;
#pragma unroll
    for (int s = 0; s < NSLOT; ++s) Ls += Lacc[s];
    float invL = 1.0f / Ls;
    const f32x4* pre4 = (const f32x4*)preact;
    f32x4 fg = pre4[tid];
    f32x4 ig = pre4[256 + tid];
    f32x4 og = pre4[512 + tid];
    f32x4 rg = pre4[768 + tid];
    f32x4 gg = pre4[1024 + tid];
    f32x4 m4 = {0.f, 0.f, 0.f, 0.f};
#pragma unroll
    for (int s = 0; s < NSLOT; ++s) m4 += ((const f32x4*)(macc + (size_t)s * NHID))[tid];
    f32x4 c4 = ((const f32x4*)c_in)[tid];
    f32x4 h4, ct4;
#pragma unroll
    for (int e = 0; e < 4; ++e) {
        float f = sigm(fg[e]);
        float i = sigm(ig[e]);
        float o = sigm(og[e]);
        float r = sigm(rg[e]);
        float cn = tanhf(gg[e]);
        float mt = tanhf(m4[e] * invL);
        float ct = f * c4[e] + i * cn + r * mt;
        ct4[e] = ct;
        h4[e] = o * tanhf(ct);
    }
    ((f32x4*)hlds)[tid] = h4;
    if (blockIdx.x == 0) {
        ((f32x4*)(out + 4))[tid] = h4;
        ((f32x4*)(out + 4 + NHID))[tid] = ct4;
    }
    __syncthreads();
    int wave = tid >> 6, lane = tid & 63;
    int row = blockIdx.x * 4 + wave;
    const f32x4* w4 = (const f32x4*)(Wih + (size_t)row * NHID);
    const f32x4* hl4 = (const f32x4*)hlds;
    float p = 0.f;
#pragma unroll
    for (int j = 0; j < 4; ++j) {
        f32x4 wv = __builtin_nontemporal_load(&w4[j * 64 + lane]);
        f32x4 hv = hl4[j * 64 + lane];
        p += wv.x * hv.x + wv.y * hv.y + wv.z * hv.z + wv.w * hv.w;
    }
    p = wave_reduce_sum(p);
    if (lane == 0) hh[row] = fmaxf(p + bih[row], 0.f);
}

#define TF_ROUND(r) { x0 += x1; x1 = (x1 << r) | (x1 >> (32 - r)); x1 ^= x0; }

// actor/critic heads + jax.random.categorical(key(1), log pi) replication
__global__ void k6_heads(const float* __restrict__ hh, const float* __restrict__ Wa,
                         const float* __restrict__ ba, const float* __restrict__ Wc,
                         const float* __restrict__ bc, float* __restrict__ out) {
    __shared__ float zz[3];
    int wave = threadIdx.x >> 6, lane = threadIdx.x & 63;
    if (wave < 3) {
        const float* W = (wave == 2) ? Wc : Wa + wave * NHID;
        const f32x4* w4 = (const f32x4*)W;
        const f32x4* h4 = (const f32x4*)hh;
        float p = 0.f;
#pragma unroll
        for (int j = 0; j < 4; ++j) {
            f32x4 wv = w4[j * 64 + lane];
            f32x4 hv = h4[j * 64 + lane];
            p += wv.x * hv.x + wv.y * hv.y + wv.z * hv.z + wv.w * hv.w;
        }
        p = wave_reduce_sum(p);
        if (lane == 0) zz[wave] = p;
    }
    __syncthreads();
    if (threadIdx.x == 0) {
        float z0 = zz[0] + ba[0], z1 = zz[1] + ba[1], v = zz[2] + bc[0];
        float mz = fmaxf(z0, z1);
        float e0 = expf(z0 - mz), e1 = expf(z1 - mz);
        float sum = e0 + e1;
        float pi0 = e0 / sum, pi1 = e1 / sum;
        float lse = mz + logf(sum);
        // Threefry-2x32, key = (0,1) [jax.random.key(1)], counter = (0,1)
        unsigned ks0 = 0u, ks1 = 1u, ks2 = 0u ^ 1u ^ 0x1BD11BDAu;
        unsigned x0 = 0u + ks0, x1 = 1u + ks1;
        TF_ROUND(13) TF_ROUND(15) TF_ROUND(26) TF_ROUND(6)
        x0 += ks1; x1 += ks2 + 1u;
        TF_ROUND(17) TF_ROUND(29) TF_ROUND(16) TF_ROUND(24)
        x0 += ks2; x1 += ks0 + 2u;
        TF_ROUND(13) TF_ROUND(15) TF_ROUND(26) TF_ROUND(6)
        x0 += ks0; x1 += ks1 + 3u;
        TF_ROUND(17) TF_ROUND(29) TF_ROUND(16) TF_ROUND(24)
        x0 += ks1; x1 += ks2 + 4u;
        TF_ROUND(13) TF_ROUND(15) TF_ROUND(26) TF_ROUND(6)
        x0 += ks2; x1 += ks0 + 5u;
        float u0 = __uint_as_float((x0 >> 9) | 0x3F800000u) - 1.0f;
        float u1 = __uint_as_float((x1 >> 9) | 0x3F800000u) - 1.0f;
        const float tiny = 1.17549435e-38f;
        u0 = fmaxf(u0, tiny); u1 = fmaxf(u1, tiny);
        float g0 = -logf(-logf(u0));
        float g1 = -logf(-logf(u1));
        int a = (z1 + g1 > z0 + g0) ? 1 : 0;
        float logp = (a ? z1 : z0) - lse;
        out[0] = pi0; out[1] = pi1; out[2] = v; out[3] = logp;
    }
}

extern "C" void kernel_launch(void* const* d_in, const int* in_sizes, int n_in,
                              void* d_out, int out_size, void* d_ws, size_t ws_size,
                              hipStream_t stream) {
    const float* x      = (const float*)d_in[0];
    const float* h      = (const float*)d_in[1];
    const float* c      = (const float*)d_in[2];
    const float* keys   = (const float*)d_in[3];
    const float* vals   = (const float*)d_in[4];
    const float* Wi2h   = (const float*)d_in[5];
    const float* bi2h   = (const float*)d_in[6];
    const float* Wh2h   = (const float*)d_in[7];
    const float* bh2h   = (const float*)d_in[8];
    const float* Wih    = (const float*)d_in[9];
    const float* bih    = (const float*)d_in[10];
    const float* Wact   = (const float*)d_in[11];
    const float* bact   = (const float*)d_in[12];
    const float* Wcrit  = (const float*)d_in[13];
    const float* bcrit  = (const float*)d_in[14];
    const int*   pick   = (const int*)d_in[15];
    float* out = (float*)d_out;
    float* ws  = (float*)d_ws;

    (void)hipMemsetAsync(ws, 0, ZERO_BYTES, stream);
    kA<<<NB3 + NBPRE, 256, 0, stream>>>(keys, x, pick, vals,
                                        ws + WS_MACC, ws + WS_L,
                                        h, Wi2h, bi2h, Wh2h, bh2h, ws + WS_PREACT);
    k45<<<NHID / 4, 256, 0, stream>>>(ws + WS_PREACT, ws + WS_MACC, ws + WS_L,
                                      c, Wih, bih, out, ws + WS_HH);
    k6_heads<<<1, 256, 0, stream>>>(ws + WS_HH, Wact, bact, Wcrit, bcrit, out);
}

// Round 12
// 94.583 us; speedup vs baseline: 1.0449x; 1.0449x over previous
//
#include <hip/hip_runtime.h>
#include <math.h>

#define NHID 1024
#define NIN 14
#define NKEYS 100000
#define NRD 10
#define R3 100           // rows per PV block; 1000 * 100 = 100000 exactly
#define NB3 1000
#define NBPRE 1280       // 5120 preact rows / 4 per block
#define NSLOT 8
#define GRP 10           // rows per stream group (double-buffered banks)

typedef float f32x4 __attribute__((ext_vector_type(4)));
typedef float f32x2 __attribute__((ext_vector_type(2)));

// ws float-index layout
#define WS_MACC    0         // NSLOT*1024 = 8192 floats
#define WS_L       8192      // NSLOT floats
#define WS_PREACT  8208      // 5120 floats (16B aligned)
#define WS_HH      13328     // 1024
#define ZERO_BYTES ((NSLOT * NHID + NSLOT) * 4)

__device__ inline float wave_reduce_sum(float v) {
#pragma unroll
    for (int off = 32; off > 0; off >>= 1) v += __shfl_down(v, off, 64);
    return v;
}

__device__ inline float sigm(float x) { return 1.0f / (1.0f + expf(-x)); }

__device__ inline float bcast_lane(float v, int lane) {
    return __uint_as_float(__builtin_amdgcn_readlane(__float_as_uint(v), lane));
}

// native f32 atomic add (global_atomic_add_f32), not a CAS loop
__device__ inline void atomAddF(float* p, float v) { unsafeAtomicAdd(p, v); }

// load q (clamped dynamic_slice like JAX) and its norm
__device__ inline float load_q(const float* __restrict__ x, int pick, float* q) {
    int start = pick * NRD;
    if (start > NIN - NRD) start = NIN - NRD;
    if (start < 0) start = 0;
    float qn = 0.f;
#pragma unroll
    for (int k = 0; k < NRD; ++k) { q[k] = x[start + k]; qn = fmaf(q[k], q[k], qn); }
    return sqrtf(qn);
}

// cosine score, f32x2 key loads (rows are 40B -> always 8B aligned)
__device__ inline float score2(const float* __restrict__ keys, int i,
                               const float* q, float qn) {
    const f32x2* kp = (const f32x2*)(keys + (size_t)i * NRD);
    float dot = 0.f, kn = 0.f;
#pragma unroll
    for (int k = 0; k < 5; ++k) {
        f32x2 kv = kp[k];
        dot = fmaf(kv.x, q[2 * k], fmaf(kv.y, q[2 * k + 1], dot));
        kn  = fmaf(kv.x, kv.x, fmaf(kv.y, kv.y, kn));
    }
    return dot / fmaxf(sqrtf(kn) * qn, 1e-8f);
}

// Fused kernel. ROLE ORDER MATTERS (R12): blocks [0, NBPRE) do the SHORT
// preact GEMV rows and are placed first so they retire in the first ~3 µs
// (only ~1024 of 2280 blocks are resident at 4 blocks/CU; if the long PV
// blocks came first, ~1256 preact blocks would serialize into a tail AFTER
// the 70 µs PV stream). Blocks [NBPRE, NBPRE+NB3) do the PV partial
// reduction (unnormalized; cos-sim scores in [-1,1], exp stable, no max
// pass), double-buffered nontemporal stream (nt confirmed +8.5 µs by R11
// A/B), weight broadcast via v_readlane, no LDS, no __syncthreads.
// NOTE (R7/R9): NO threadfence/ACQ_REL election — ~20 µs at any scale.
__global__ void __launch_bounds__(256) kA(const float* __restrict__ keys,
                                          const float* __restrict__ x,
                                          const int* __restrict__ pick_arm,
                                          const float* __restrict__ vals,
                                          float* __restrict__ macc,
                                          float* __restrict__ Lacc,
                                          const float* __restrict__ h,
                                          const float* __restrict__ Wi,
                                          const float* __restrict__ bi,
                                          const float* __restrict__ Wh,
                                          const float* __restrict__ bh,
                                          float* __restrict__ preact) {
    int tid = threadIdx.x;
    if (blockIdx.x >= NBPRE) {
        int b = blockIdx.x - NBPRE;
        int r0 = b * R3;
        int slot = b & (NSLOT - 1);
        int lane = tid & 63;
        const f32x4* vp = (const f32x4*)vals + ((size_t)r0 << 8) + tid;
        f32x4 bankA[GRP], bankB[GRP];
        // prologue: issue group 0 into bank A before any score work
#pragma unroll
        for (int j = 0; j < GRP; ++j)
            bankA[j] = __builtin_nontemporal_load(&vp[(size_t)j << 8]);
        __builtin_amdgcn_sched_barrier(0);
        // redundant per-wave score computation, all 64 lanes (keys L2-hot)
        float q[NRD];
        float qn = load_q(x, pick_arm[0], q);
        float wva = expf(score2(keys, r0 + lane, q, qn));        // rows 0..63
        float wvb = 0.f;
        if (lane < R3 - 64)                                      // rows 64..99
            wvb = expf(score2(keys, r0 + 64 + lane, q, qn));
        if (tid < 64) {                  // wave 0 contributes the L partial
            float ls = wave_reduce_sum(wva + wvb);
            if (tid == 0) atomAddF(&Lacc[slot], ls);
        }
        float ax = 0.f, ay = 0.f, az = 0.f, aw = 0.f;
#pragma unroll
        for (int g = 0; g < R3 / GRP; ++g) {
            // issue group g+1 into the other bank (static bank choice)
            if (g + 1 < R3 / GRP) {
                if (g & 1) {
#pragma unroll
                    for (int j = 0; j < GRP; ++j)
                        bankA[j] = __builtin_nontemporal_load(
                            &vp[(size_t)((g + 1) * GRP + j) << 8]);
                } else {
#pragma unroll
                    for (int j = 0; j < GRP; ++j)
                        bankB[j] = __builtin_nontemporal_load(
                            &vp[(size_t)((g + 1) * GRP + j) << 8]);
                }
            }
            __builtin_amdgcn_sched_barrier(0);
            // consume group g from this bank
#pragma unroll
            for (int j = 0; j < GRP; ++j) {
                int r = g * GRP + j;
                float w = (r < 64) ? bcast_lane(wva, r) : bcast_lane(wvb, r - 64);
                f32x4 v = (g & 1) ? bankB[j] : bankA[j];
                ax = fmaf(w, v.x, ax);
                ay = fmaf(w, v.y, ay);
                az = fmaf(w, v.z, az);
                aw = fmaf(w, v.w, aw);
            }
            __builtin_amdgcn_sched_barrier(0);
        }
        float* ms = macc + (size_t)slot * NHID;
        atomAddF(&ms[4 * tid + 0], ax);
        atomAddF(&ms[4 * tid + 1], ay);
        atomAddF(&ms[4 * tid + 2], az);
        atomAddF(&ms[4 * tid + 3], aw);
    } else {
        int wave = tid >> 6, lane = tid & 63;
        int row = blockIdx.x * 4 + wave;
        const f32x4* w4 = (const f32x4*)(Wh + (size_t)row * NHID);
        const f32x4* h4 = (const f32x4*)h;
        float p = 0.f;
#pragma unroll
        for (int j = 0; j < 4; ++j) {
            f32x4 wv = __builtin_nontemporal_load(&w4[j * 64 + lane]);
            f32x4 hv = h4[j * 64 + lane];
            p += wv.x * hv.x + wv.y * hv.y + wv.z * hv.z + wv.w * hv.w;
        }
        if (lane < NIN) p += x[lane] * Wi[(size_t)row * NIN + lane];
        p = wave_reduce_sum(p);
        if (lane == 0) preact[row] = p + bi[row] + bh[row];
    }
}

// Fused cell update + hidden GEMV. Every block redundantly computes the full
// 1024-wide cell update (L2-hot inputs), stashes h_t in LDS, then computes its
// 4 rows of hh = relu(W_ih . h_t + b_ih). Block 0 also writes h_t/c_t to out.
__global__ void __launch_bounds__(256) k45(const float* __restrict__ preact,
                                           const float* __restrict__ macc,
                                           const float* __restrict__ Lacc,
                                           const float* __restrict__ c_in,
                                           const float* __restrict__ Wih,
                                           const float* __restrict__ bih,
                                           float* __restrict__ out,
                                           float* __restrict__ hh) {
    __shared__ float hlds[NHID];
    int tid = threadIdx.x;
    float Ls = 0.f;
#pragma unroll
    for (int s = 0; s < NSLOT; ++s) Ls += Lacc[s];
    float invL = 1.0f / Ls;
    const f32x4* pre4 = (const f32x4*)preact;
    f32x4 fg = pre4[tid];
    f32x4 ig = pre4[256 + tid];
    f32x4 og = pre4[512 + tid];
    f32x4 rg = pre4[768 + tid];
    f32x4 gg = pre4[1024 + tid];
    f32x4 m4 = {0.f, 0.f, 0.f, 0.f};
#pragma unroll
    for (int s = 0; s < NSLOT; ++s) m4 += ((const f32x4*)(macc + (size_t)s * NHID))[tid];
    f32x4 c4 = ((const f32x4*)c_in)[tid];
    f32x4 h4, ct4;
#pragma unroll
    for (int e = 0; e < 4; ++e) {
        float f = sigm(fg[e]);
        float i = sigm(ig[e]);
        float o = sigm(og[e]);
        float r = sigm(rg[e]);
        float cn = tanhf(gg[e]);
        float mt = tanhf(m4[e] * invL);
        float ct = f * c4[e] + i * cn + r * mt;
        ct4[e] = ct;
        h4[e] = o * tanhf(ct);
    }
    ((f32x4*)hlds)[tid] = h4;
    if (blockIdx.x == 0) {
        ((f32x4*)(out + 4))[tid] = h4;
        ((f32x4*)(out + 4 + NHID))[tid] = ct4;
    }
    __syncthreads();
    int wave = tid >> 6, lane = tid & 63;
    int row = blockIdx.x * 4 + wave;
    const f32x4* w4 = (const f32x4*)(Wih + (size_t)row * NHID);
    const f32x4* hl4 = (const f32x4*)hlds;
    float p = 0.f;
#pragma unroll
    for (int j = 0; j < 4; ++j) {
        f32x4 wv = __builtin_nontemporal_load(&w4[j * 64 + lane]);
        f32x4 hv = hl4[j * 64 + lane];
        p += wv.x * hv.x + wv.y * hv.y + wv.z * hv.z + wv.w * hv.w;
    }
    p = wave_reduce_sum(p);
    if (lane == 0) hh[row] = fmaxf(p + bih[row], 0.f);
}

#define TF_ROUND(r) { x0 += x1; x1 = (x1 << r) | (x1 >> (32 - r)); x1 ^= x0; }

// actor/critic heads + jax.random.categorical(key(1), log pi) replication
__global__ void k6_heads(const float* __restrict__ hh, const float* __restrict__ Wa,
                         const float* __restrict__ ba, const float* __restrict__ Wc,
                         const float* __restrict__ bc, float* __restrict__ out) {
    __shared__ float zz[3];
    int wave = threadIdx.x >> 6, lane = threadIdx.x & 63;
    if (wave < 3) {
        const float* W = (wave == 2) ? Wc : Wa + wave * NHID;
        const f32x4* w4 = (const f32x4*)W;
        const f32x4* h4 = (const f32x4*)hh;
        float p = 0.f;
#pragma unroll
        for (int j = 0; j < 4; ++j) {
            f32x4 wv = w4[j * 64 + lane];
            f32x4 hv = h4[j * 64 + lane];
            p += wv.x * hv.x + wv.y * hv.y + wv.z * hv.z + wv.w * hv.w;
        }
        p = wave_reduce_sum(p);
        if (lane == 0) zz[wave] = p;
    }
    __syncthreads();
    if (threadIdx.x == 0) {
        float z0 = zz[0] + ba[0], z1 = zz[1] + ba[1], v = zz[2] + bc[0];
        float mz = fmaxf(z0, z1);
        float e0 = expf(z0 - mz), e1 = expf(z1 - mz);
        float sum = e0 + e1;
        float pi0 = e0 / sum, pi1 = e1 / sum;
        float lse = mz + logf(sum);
        // Threefry-2x32, key = (0,1) [jax.random.key(1)], counter = (0,1)
        unsigned ks0 = 0u, ks1 = 1u, ks2 = 0u ^ 1u ^ 0x1BD11BDAu;
        unsigned x0 = 0u + ks0, x1 = 1u + ks1;
        TF_ROUND(13) TF_ROUND(15) TF_ROUND(26) TF_ROUND(6)
        x0 += ks1; x1 += ks2 + 1u;
        TF_ROUND(17) TF_ROUND(29) TF_ROUND(16) TF_ROUND(24)
        x0 += ks2; x1 += ks0 + 2u;
        TF_ROUND(13) TF_ROUND(15) TF_ROUND(26) TF_ROUND(6)
        x0 += ks0; x1 += ks1 + 3u;
        TF_ROUND(17) TF_ROUND(29) TF_ROUND(16) TF_ROUND(24)
        x0 += ks1; x1 += ks2 + 4u;
        TF_ROUND(13) TF_ROUND(15) TF_ROUND(26) TF_ROUND(6)
        x0 += ks2; x1 += ks0 + 5u;
        float u0 = __uint_as_float((x0 >> 9) | 0x3F800000u) - 1.0f;
        float u1 = __uint_as_float((x1 >> 9) | 0x3F800000u) - 1.0f;
        const float tiny = 1.17549435e-38f;
        u0 = fmaxf(u0, tiny); u1 = fmaxf(u1, tiny);
        float g0 = -logf(-logf(u0));
        float g1 = -logf(-logf(u1));
        int a = (z1 + g1 > z0 + g0) ? 1 : 0;
        float logp = (a ? z1 : z0) - lse;
        out[0] = pi0; out[1] = pi1; out[2] = v; out[3] = logp;
    }
}

extern "C" void kernel_launch(void* const* d_in, const int* in_sizes, int n_in,
                              void* d_out, int out_size, void* d_ws, size_t ws_size,
                              hipStream_t stream) {
    const float* x      = (const float*)d_in[0];
    const float* h      = (const float*)d_in[1];
    const float* c      = (const float*)d_in[2];
    const float* keys   = (const float*)d_in[3];
    const float* vals   = (const float*)d_in[4];
    const float* Wi2h   = (const float*)d_in[5];
    const float* bi2h   = (const float*)d_in[6];
    const float* Wh2h   = (const float*)d_in[7];
    const float* bh2h   = (const float*)d_in[8];
    const float* Wih    = (const float*)d_in[9];
    const float* bih    = (const float*)d_in[10];
    const float* Wact   = (const float*)d_in[11];
    const float* bact   = (const float*)d_in[12];
    const float* Wcrit  = (const float*)d_in[13];
    const float* bcrit  = (const float*)d_in[14];
    const int*   pick   = (const int*)d_in[15];
    float* out = (float*)d_out;
    float* ws  = (float*)d_ws;

    (void)hipMemsetAsync(ws, 0, ZERO_BYTES, stream);
    kA<<<NBPRE + NB3, 256, 0, stream>>>(keys, x, pick, vals,
                                        ws + WS_MACC, ws + WS_L,
                                        h, Wi2h, bi2h, Wh2h, bh2h, ws + WS_PREACT);
    k45<<<NHID / 4, 256, 0, stream>>>(ws + WS_PREACT, ws + WS_MACC, ws + WS_L,
                                      c, Wih, bih, out, ws + WS_HH);
    k6_heads<<<1, 256, 0, stream>>>(ws + WS_HH, Wact, bact, Wcrit, bcrit, out);
}

// Round 13
// 90.183 us; speedup vs baseline: 1.0958x; 1.0488x over previous
//
#include <hip/hip_runtime.h>
#include <math.h>

#define NHID 1024
#define NIN 14
#define NKEYS 100000
#define NRD 10
#define R3 100           // rows per PV block; 1000 * 100 = 100000 exactly
#define NB3 1000
#define NBPRE 1280       // 5120 preact rows / 4 per block
#define NSLOT 8
#define GRP 10           // rows per stream group (double-buffered banks)

typedef float f32x4 __attribute__((ext_vector_type(4)));
typedef float f32x2 __attribute__((ext_vector_type(2)));

// ws float-index layout
#define WS_MACC    0         // NSLOT*1024 = 8192 floats
#define WS_L       8192      // NSLOT floats
#define WS_PREACT  8208      // 5120 floats (16B aligned)
#define WS_HH      13328     // 1024
#define ZERO_BYTES ((NSLOT * NHID + NSLOT) * 4)

__device__ inline float wave_reduce_sum(float v) {
#pragma unroll
    for (int off = 32; off > 0; off >>= 1) v += __shfl_down(v, off, 64);
    return v;
}

__device__ inline float sigm(float x) { return 1.0f / (1.0f + expf(-x)); }

__device__ inline float bcast_lane(float v, int lane) {
    return __uint_as_float(__builtin_amdgcn_readlane(__float_as_uint(v), lane));
}

// native f32 atomic add (global_atomic_add_f32), not a CAS loop
__device__ inline void atomAddF(float* p, float v) { unsafeAtomicAdd(p, v); }

// load q (clamped dynamic_slice like JAX) and its norm
__device__ inline float load_q(const float* __restrict__ x, int pick, float* q) {
    int start = pick * NRD;
    if (start > NIN - NRD) start = NIN - NRD;
    if (start < 0) start = 0;
    float qn = 0.f;
#pragma unroll
    for (int k = 0; k < NRD; ++k) { q[k] = x[start + k]; qn = fmaf(q[k], q[k], qn); }
    return sqrtf(qn);
}

// cosine score, f32x2 key loads (rows are 40B -> always 8B aligned)
__device__ inline float score2(const float* __restrict__ keys, int i,
                               const float* q, float qn) {
    const f32x2* kp = (const f32x2*)(keys + (size_t)i * NRD);
    float dot = 0.f, kn = 0.f;
#pragma unroll
    for (int k = 0; k < 5; ++k) {
        f32x2 kv = kp[k];
        dot = fmaf(kv.x, q[2 * k], fmaf(kv.y, q[2 * k + 1], dot));
        kn  = fmaf(kv.x, kv.x, fmaf(kv.y, kv.y, kn));
    }
    return dot / fmaxf(sqrtf(kn) * qn, 1e-8f);
}

// Fused: blocks [0, NB3) do the PV partial reduction (unnormalized; cos-sim
// scores are in [-1,1] so exp(s) is stable, no max pass); blocks
// [NB3, NB3+NBPRE) compute preact rows. ROLE ORDER (R12 A/B): long PV blocks
// FIRST — short preact blocks backfill during the stream; preact-first costs
// +4 µs. vals loads are NONTEMPORAL (R11 A/B: dropping nt costs +8.5 µs).
// NOTE (R7/R9): NO threadfence/ACQ_REL election — device-scope fences cost
// ~70 ns/block serialized; kernel boundaries are cheaper at every scale.
__global__ void __launch_bounds__(256) kA(const float* __restrict__ keys,
                                          const float* __restrict__ x,
                                          const int* __restrict__ pick_arm,
                                          const float* __restrict__ vals,
                                          float* __restrict__ macc,
                                          float* __restrict__ Lacc,
                                          const float* __restrict__ h,
                                          const float* __restrict__ Wi,
                                          const float* __restrict__ bi,
                                          const float* __restrict__ Wh,
                                          const float* __restrict__ bh,
                                          float* __restrict__ preact) {
    int tid = threadIdx.x;
    if (blockIdx.x < NB3) {
        int r0 = blockIdx.x * R3;
        int slot = blockIdx.x & (NSLOT - 1);
        int lane = tid & 63;
        const f32x4* vp = (const f32x4*)vals + ((size_t)r0 << 8) + tid;
        f32x4 bankA[GRP], bankB[GRP];
        // prologue: issue group 0 into bank A before any score work
#pragma unroll
        for (int j = 0; j < GRP; ++j)
            bankA[j] = __builtin_nontemporal_load(&vp[(size_t)j << 8]);
        __builtin_amdgcn_sched_barrier(0);
        // redundant per-wave score computation, all 64 lanes (keys L2-hot)
        float q[NRD];
        float qn = load_q(x, pick_arm[0], q);
        float wva = expf(score2(keys, r0 + lane, q, qn));        // rows 0..63
        float wvb = 0.f;
        if (lane < R3 - 64)                                      // rows 64..99
            wvb = expf(score2(keys, r0 + 64 + lane, q, qn));
        if (tid < 64) {                  // wave 0 contributes the L partial
            float ls = wave_reduce_sum(wva + wvb);
            if (tid == 0) atomAddF(&Lacc[slot], ls);
        }
        float ax = 0.f, ay = 0.f, az = 0.f, aw = 0.f;
#pragma unroll
        for (int g = 0; g < R3 / GRP; ++g) {
            // issue group g+1 into the other bank (static bank choice)
            if (g + 1 < R3 / GRP) {
                if (g & 1) {
#pragma unroll
                    for (int j = 0; j < GRP; ++j)
                        bankA[j] = __builtin_nontemporal_load(
                            &vp[(size_t)((g + 1) * GRP + j) << 8]);
                } else {
#pragma unroll
                    for (int j = 0; j < GRP; ++j)
                        bankB[j] = __builtin_nontemporal_load(
                            &vp[(size_t)((g + 1) * GRP + j) << 8]);
                }
            }
            __builtin_amdgcn_sched_barrier(0);
            // consume group g from this bank
#pragma unroll
            for (int j = 0; j < GRP; ++j) {
                int r = g * GRP + j;
                float w = (r < 64) ? bcast_lane(wva, r) : bcast_lane(wvb, r - 64);
                f32x4 v = (g & 1) ? bankB[j] : bankA[j];
                ax = fmaf(w, v.x, ax);
                ay = fmaf(w, v.y, ay);
                az = fmaf(w, v.z, az);
                aw = fmaf(w, v.w, aw);
            }
            __builtin_amdgcn_sched_barrier(0);
        }
        float* ms = macc + (size_t)slot * NHID;
        atomAddF(&ms[4 * tid + 0], ax);
        atomAddF(&ms[4 * tid + 1], ay);
        atomAddF(&ms[4 * tid + 2], az);
        atomAddF(&ms[4 * tid + 3], aw);
    } else {
        int wave = tid >> 6, lane = tid & 63;
        int row = (blockIdx.x - NB3) * 4 + wave;
        const f32x4* w4 = (const f32x4*)(Wh + (size_t)row * NHID);
        const f32x4* h4 = (const f32x4*)h;
        float p = 0.f;
#pragma unroll
        for (int j = 0; j < 4; ++j) {
            f32x4 wv = __builtin_nontemporal_load(&w4[j * 64 + lane]);
            f32x4 hv = h4[j * 64 + lane];
            p += wv.x * hv.x + wv.y * hv.y + wv.z * hv.z + wv.w * hv.w;
        }
        if (lane < NIN) p += x[lane] * Wi[(size_t)row * NIN + lane];
        p = wave_reduce_sum(p);
        if (lane == 0) preact[row] = p + bi[row] + bh[row];
    }
}

// Fused cell update + hidden GEMV. Every block redundantly computes the full
// 1024-wide cell update (L2-hot inputs), stashes h_t in LDS, then computes its
// 4 rows of hh = relu(W_ih . h_t + b_ih). Block 0 also writes h_t/c_t to out.
__global__ void __launch_bounds__(256) k45(const float* __restrict__ preact,
                                           const float* __restrict__ macc,
                                           const float* __restrict__ Lacc,
                                           const float* __restrict__ c_in,
                                           const float* __restrict__ Wih,
                                           const float* __restrict__ bih,
                                           float* __restrict__ out,
                                           float* __restrict__ hh) {
    __shared__ float hlds[NHID];
    int tid = threadIdx.x;
    float Ls = 0.f;
#pragma unroll
    for (int s = 0; s < NSLOT; ++s) Ls += Lacc[s];
    float invL = 1.0f / Ls;
    const f32x4* pre4 = (const f32x4*)preact;
    f32x4 fg = pre4[tid];
    f32x4 ig = pre4[256 + tid];
    f32x4 og = pre4[512 + tid];
    f32x4 rg = pre4[768 + tid];
    f32x4 gg = pre4[1024 + tid];
    f32x4 m4 = {0.f, 0.f, 0.f, 0.f};
#pragma unroll
    for (int s = 0; s < NSLOT; ++s) m4 += ((const f32x4*)(macc + (size_t)s * NHID))[tid];
    f32x4 c4 = ((const f32x4*)c_in)[tid];
    f32x4 h4, ct4;
#pragma unroll
    for (int e = 0; e < 4; ++e) {
        float f = sigm(fg[e]);
        float i = sigm(ig[e]);
        float o = sigm(og[e]);
        float r = sigm(rg[e]);
        float cn = tanhf(gg[e]);
        float mt = tanhf(m4[e] * invL);
        float ct = f * c4[e] + i * cn + r * mt;
        ct4[e] = ct;
        h4[e] = o * tanhf(ct);
    }
    ((f32x4*)hlds)[tid] = h4;
    if (blockIdx.x == 0) {
        ((f32x4*)(out + 4))[tid] = h4;
        ((f32x4*)(out + 4 + NHID))[tid] = ct4;
    }
    __syncthreads();
    int wave = tid >> 6, lane = tid & 63;
    int row = blockIdx.x * 4 + wave;
    const f32x4* w4 = (const f32x4*)(Wih + (size_t)row * NHID);
    const f32x4* hl4 = (const f32x4*)hlds;
    float p = 0.f;
#pragma unroll
    for (int j = 0; j < 4; ++j) {
        f32x4 wv = __builtin_nontemporal_load(&w4[j * 64 + lane]);
        f32x4 hv = hl4[j * 64 + lane];
        p += wv.x * hv.x + wv.y * hv.y + wv.z * hv.z + wv.w * hv.w;
    }
    p = wave_reduce_sum(p);
    if (lane == 0) hh[row] = fmaxf(p + bih[row], 0.f);
}

#define TF_ROUND(r) { x0 += x1; x1 = (x1 << r) | (x1 >> (32 - r)); x1 ^= x0; }

// actor/critic heads + jax.random.categorical(key(1), log pi) replication
__global__ void k6_heads(const float* __restrict__ hh, const float* __restrict__ Wa,
                         const float* __restrict__ ba, const float* __restrict__ Wc,
                         const float* __restrict__ bc, float* __restrict__ out) {
    __shared__ float zz[3];
    int wave = threadIdx.x >> 6, lane = threadIdx.x & 63;
    if (wave < 3) {
        const float* W = (wave == 2) ? Wc : Wa + wave * NHID;
        const f32x4* w4 = (const f32x4*)W;
        const f32x4* h4 = (const f32x4*)hh;
        float p = 0.f;
#pragma unroll
        for (int j = 0; j < 4; ++j) {
            f32x4 wv = w4[j * 64 + lane];
            f32x4 hv = h4[j * 64 + lane];
            p += wv.x * hv.x + wv.y * hv.y + wv.z * hv.z + wv.w * hv.w;
        }
        p = wave_reduce_sum(p);
        if (lane == 0) zz[wave] = p;
    }
    __syncthreads();
    if (threadIdx.x == 0) {
        float z0 = zz[0] + ba[0], z1 = zz[1] + ba[1], v = zz[2] + bc[0];
        float mz = fmaxf(z0, z1);
        float e0 = expf(z0 - mz), e1 = expf(z1 - mz);
        float sum = e0 + e1;
        float pi0 = e0 / sum, pi1 = e1 / sum;
        float lse = mz + logf(sum);
        // Threefry-2x32, key = (0,1) [jax.random.key(1)], counter = (0,1)
        unsigned ks0 = 0u, ks1 = 1u, ks2 = 0u ^ 1u ^ 0x1BD11BDAu;
        unsigned x0 = 0u + ks0, x1 = 1u + ks1;
        TF_ROUND(13) TF_ROUND(15) TF_ROUND(26) TF_ROUND(6)
        x0 += ks1; x1 += ks2 + 1u;
        TF_ROUND(17) TF_ROUND(29) TF_ROUND(16) TF_ROUND(24)
        x0 += ks2; x1 += ks0 + 2u;
        TF_ROUND(13) TF_ROUND(15) TF_ROUND(26) TF_ROUND(6)
        x0 += ks0; x1 += ks1 + 3u;
        TF_ROUND(17) TF_ROUND(29) TF_ROUND(16) TF_ROUND(24)
        x0 += ks1; x1 += ks2 + 4u;
        TF_ROUND(13) TF_ROUND(15) TF_ROUND(26) TF_ROUND(6)
        x0 += ks2; x1 += ks0 + 5u;
        float u0 = __uint_as_float((x0 >> 9) | 0x3F800000u) - 1.0f;
        float u1 = __uint_as_float((x1 >> 9) | 0x3F800000u) - 1.0f;
        const float tiny = 1.17549435e-38f;
        u0 = fmaxf(u0, tiny); u1 = fmaxf(u1, tiny);
        float g0 = -logf(-logf(u0));
        float g1 = -logf(-logf(u1));
        int a = (z1 + g1 > z0 + g0) ? 1 : 0;
        float logp = (a ? z1 : z0) - lse;
        out[0] = pi0; out[1] = pi1; out[2] = v; out[3] = logp;
    }
}

extern "C" void kernel_launch(void* const* d_in, const int* in_sizes, int n_in,
                              void* d_out, int out_size, void* d_ws, size_t ws_size,
                              hipStream_t stream) {
    const float* x      = (const float*)d_in[0];
    const float* h      = (const float*)d_in[1];
    const float* c      = (const float*)d_in[2];
    const float* keys   = (const float*)d_in[3];
    const float* vals   = (const float*)d_in[4];
    const float* Wi2h   = (const float*)d_in[5];
    const float* bi2h   = (const float*)d_in[6];
    const float* Wh2h   = (const float*)d_in[7];
    const float* bh2h   = (const float*)d_in[8];
    const float* Wih    = (const float*)d_in[9];
    const float* bih    = (const float*)d_in[10];
    const float* Wact   = (const float*)d_in[11];
    const float* bact   = (const float*)d_in[12];
    const float* Wcrit  = (const float*)d_in[13];
    const float* bcrit  = (const float*)d_in[14];
    const int*   pick   = (const int*)d_in[15];
    float* out = (float*)d_out;
    float* ws  = (float*)d_ws;

    (void)hipMemsetAsync(ws, 0, ZERO_BYTES, stream);
    kA<<<NB3 + NBPRE, 256, 0, stream>>>(keys, x, pick, vals,
                                        ws + WS_MACC, ws + WS_L,
                                        h, Wi2h, bi2h, Wh2h, bh2h, ws + WS_PREACT);
    k45<<<NHID / 4, 256, 0, stream>>>(ws + WS_PREACT, ws + WS_MACC, ws + WS_L,
                                      c, Wih, bih, out, ws + WS_HH);
    k6_heads<<<1, 256, 0, stream>>>(ws + WS_HH, Wact, bact, Wcrit, bcrit, out);
}